// Round 1
// baseline (551.764 us; speedup 1.0000x reference)
//
#include <hip/hip_runtime.h>
#include <hip/hip_fp16.h>

typedef unsigned short u16;
typedef __attribute__((ext_vector_type(8))) _Float16 h8;
typedef __attribute__((ext_vector_type(8))) short s16x8;
typedef __attribute__((ext_vector_type(4))) float fx4;

#define MFMA16(a,b,c) __builtin_amdgcn_mfma_f32_16x16x32_f16((a),(b),(c),0,0,0)

static __device__ __forceinline__ u16 f2hbits(float x){
  __half h = __float2half_rn(x);
  union { __half h; u16 u; } c; c.h = h; return c.u;
}
static __device__ __forceinline__ uint32_t pkh(float a, float b){
  __half2 h = __floats2half2_rn(a, b);
  union { __half2 h; uint32_t u; } c; c.h = h; return c.u;
}

// ---------------- prep: fp32 -> fp16 cast ----------------
__global__ void f2h_kernel(const float* __restrict__ in, u16* __restrict__ out, int n4){
  int i = blockIdx.x*256 + threadIdx.x;
  if (i < n4){
    float4 v = ((const float4*)in)[i];
    ushort4 o;
    o.x = f2hbits(v.x); o.y = f2hbits(v.y); o.z = f2hbits(v.z); o.w = f2hbits(v.w);
    ((ushort4*)out)[i] = o;
  }
}

// ---------------- prep: W[h][n][d] -> Wt[h*64+d][n] fp16 ----------------
__global__ void wtr_kernel(const float* __restrict__ Wq, const float* __restrict__ Wk,
                           const float* __restrict__ Wv, u16* __restrict__ Wt){
  __shared__ float tl[64][65];
  int z = blockIdx.z, h = blockIdx.y, n0 = blockIdx.x*64;
  const float* W = (z==0)?Wq:((z==1)?Wk:Wv);
  W += (size_t)h*65536;  // h * 1024 * 64
  int t = threadIdx.x;
  #pragma unroll
  for (int i=0;i<16;++i){
    int idx = t + i*256; int r = idx>>6, c = idx&63;
    tl[r][c] = W[(size_t)(n0+r)*64 + c];
  }
  __syncthreads();
  u16* O = Wt + (size_t)z*1048576 + (size_t)h*64*1024 + n0;
  #pragma unroll
  for (int i=0;i<16;++i){
    int idx = t + i*256; int r2 = idx>>6, c2 = idx&63;
    O[(size_t)r2*1024 + c2] = f2hbits(tl[c2][r2]);
  }
}

// ---------------- 128x128x(K=1024) NT GEMM, fp16 MFMA, reg-staged dbuf ----------------
// EPI==0: A=x16[8192x1024], B=Wt+z*1M, out: z0->Qb (bias, *0.125), z1->Kb (bias), z2->Vt transposed (bias)
// EPI==1: A=WO16[1024x1024], B=Ob+z*2M (z=batch), out: fp32 d_out[b][o][s] + bias0[o]
template<int EPI>
__launch_bounds__(256, 2)
__global__ void gemm_nt(const u16* __restrict__ A, const u16* __restrict__ Bbase,
                        const float* __restrict__ bias0, const float* __restrict__ bias1,
                        const float* __restrict__ bias2,
                        u16* __restrict__ out0, u16* __restrict__ out1, u16* __restrict__ out2,
                        float* __restrict__ fout){
  __shared__ __align__(16) u16 lds[16384];  // 2 bufs x (A 4096 + B 4096) halves
  const int K = 1024;
  int mt = blockIdx.x, ntile = blockIdx.y, z = blockIdx.z;
  int m0 = mt*128, n0 = ntile*128;
  const u16* Ap = A;
  const u16* Bp = (EPI==0) ? (Bbase + (size_t)z*1048576) : (Bbase + (size_t)z*2097152);
  int t = threadIdx.x;
  int lane = t & 63, wv = t>>6, g = lane>>4, q15 = lane&15;
  int wr = wv>>1, wc = wv&1;

  fx4 zero4 = {0.f,0.f,0.f,0.f};
  fx4 acc[4][4];
  #pragma unroll
  for (int i=0;i<4;++i)
    #pragma unroll
    for (int j=0;j<4;++j) acc[i][j] = zero4;

  int rowA = t>>2, col8 = (t&3)*8;
  const u16* gA0 = Ap + (size_t)(m0+rowA)*K + col8;
  const u16* gA1 = Ap + (size_t)(m0+rowA+64)*K + col8;
  const u16* gB0 = Bp + (size_t)(n0+rowA)*K + col8;
  const u16* gB1 = Bp + (size_t)(n0+rowA+64)*K + col8;

  s16x8 sa0 = *(const s16x8*)(gA0);
  s16x8 sa1 = *(const s16x8*)(gA1);
  s16x8 sb0 = *(const s16x8*)(gB0);
  s16x8 sb1 = *(const s16x8*)(gB1);
  int cur = 0;
  *(s16x8*)(lds + t*8)        = sa0;
  *(s16x8*)(lds + 2048 + t*8) = sa1;
  *(s16x8*)(lds + 4096 + t*8) = sb0;
  *(s16x8*)(lds + 6144 + t*8) = sb1;

  for (int kt=0; kt<32; ++kt){
    if (kt+1 < 32){
      int k0 = (kt+1)*32;
      sa0 = *(const s16x8*)(gA0 + k0);
      sa1 = *(const s16x8*)(gA1 + k0);
      sb0 = *(const s16x8*)(gB0 + k0);
      sb1 = *(const s16x8*)(gB1 + k0);
    }
    __syncthreads();
    const u16* bufA = lds + cur*8192;
    const u16* bufB = bufA + 4096;
    h8 af[4], bf[4];
    #pragma unroll
    for (int f=0; f<4; ++f)
      af[f] = *(const h8*)(bufA + (wr*64 + f*16 + q15)*32 + g*8);
    #pragma unroll
    for (int f=0; f<4; ++f)
      bf[f] = *(const h8*)(bufB + (wc*64 + f*16 + q15)*32 + g*8);
    #pragma unroll
    for (int i=0;i<4;++i)
      #pragma unroll
      for (int j=0;j<4;++j)
        acc[i][j] = MFMA16(af[i], bf[j], acc[i][j]);
    if (kt+1 < 32){
      u16* nb = lds + (cur^1)*8192;
      *(s16x8*)(nb + t*8)        = sa0;
      *(s16x8*)(nb + 2048 + t*8) = sa1;
      *(s16x8*)(nb + 4096 + t*8) = sb0;
      *(s16x8*)(nb + 6144 + t*8) = sb1;
      cur ^= 1;
    }
  }

  if constexpr (EPI==0){
    const float* bias = (z==0)?bias0:((z==1)?bias1:bias2);
    float bcol[4];
    #pragma unroll
    for (int fj=0;fj<4;++fj) bcol[fj] = bias[n0 + wc*64 + fj*16 + q15];
    int bb = m0 >> 11;            // batch (tiles never cross batch: 2048 % 128 == 0)
    int s_base = (m0 & 2047) + wr*64;
    if (z < 2){
      u16* o = (z==0)? out0 : out1;
      float sc = (z==0)? 0.125f : 1.0f;   // fold softmax scale into Q
      #pragma unroll
      for (int fi=0;fi<4;++fi)
        #pragma unroll
        for (int fj=0;fj<4;++fj){
          int n = n0 + wc*64 + fj*16 + q15;
          int hh = n>>6, d = n&63;
          #pragma unroll
          for (int r=0;r<4;++r){
            int s = s_base + fi*16 + g*4 + r;
            float v = (acc[fi][fj][r] + bcol[fj]) * sc;
            o[(((size_t)(bb*16+hh)*2048 + s)<<6) + d] = f2hbits(v);
          }
        }
    } else {
      // V stored transposed: Vt[b][h][d][s]
      #pragma unroll
      for (int fi=0;fi<4;++fi)
        #pragma unroll
        for (int fj=0;fj<4;++fj){
          int n = n0 + wc*64 + fj*16 + q15;
          int hh = n>>6, d = n&63;
          int s = s_base + fi*16 + g*4;
          ushort4 pk;
          pk.x = f2hbits(acc[fi][fj][0] + bcol[fj]);
          pk.y = f2hbits(acc[fi][fj][1] + bcol[fj]);
          pk.z = f2hbits(acc[fi][fj][2] + bcol[fj]);
          pk.w = f2hbits(acc[fi][fj][3] + bcol[fj]);
          *(ushort4*)(out2 + (((size_t)((bb*16+hh)*64 + d))<<11) + s) = pk;
        }
    }
  } else {
    int bb = z;
    float brow[4][4];
    #pragma unroll
    for (int fi=0;fi<4;++fi)
      #pragma unroll
      for (int r=0;r<4;++r) brow[fi][r] = bias0[m0 + wr*64 + fi*16 + g*4 + r];
    #pragma unroll
    for (int fi=0;fi<4;++fi)
      #pragma unroll
      for (int fj=0;fj<4;++fj){
        int scol = n0 + wc*64 + fj*16 + q15;
        #pragma unroll
        for (int r=0;r<4;++r){
          int orow = m0 + wr*64 + fi*16 + g*4 + r;
          fout[((size_t)bb<<21) + ((size_t)orow<<11) + scol] = acc[fi][fj][r] + brow[fi][r];
        }
      }
  }
}

// ---------------- flash attention: per block = 64 q-rows (4 waves x 16) ----------------
// Q pre-scaled by 0.125. Swapped QK^T: S^T = mfma(K, Q) -> lane holds q = lane&15.
__launch_bounds__(256, 2)
__global__ void attn_kernel(const u16* __restrict__ Qb, const u16* __restrict__ Kb,
                            const u16* __restrict__ Vt, u16* __restrict__ Ob){
  int bid = blockIdx.x;
  int qt = bid & 31, h = (bid>>5)&15, b = bid>>9;
  int t = threadIdx.x;
  int lane = t&63, wv = t>>6, g = lane>>4, q15 = lane&15;
  size_t bh = (size_t)(b*16 + h);
  const u16* Qp = Qb + (bh<<17);   // 2048*64
  const u16* Kp = Kb + (bh<<17);
  const u16* Vp = Vt + (bh<<17);   // 64*2048
  int q0 = qt*64 + wv*16;

  h8 qf[2];
  qf[0] = *(const h8*)(Qp + (size_t)(q0+q15)*64 + g*8);
  qf[1] = *(const h8*)(Qp + (size_t)(q0+q15)*64 + 32 + g*8);

  fx4 zero4 = {0.f,0.f,0.f,0.f};
  fx4 oacc[4] = {zero4, zero4, zero4, zero4};
  float m_run = -1e30f, l_run = 0.f;
  const float L2E = 1.44269504f;

  for (int kt=0; kt<32; ++kt){
    int kv0 = kt*64;
    fx4 S[4];
    #pragma unroll
    for (int kf=0; kf<4; ++kf){
      const u16* kr = Kp + (size_t)(kv0 + kf*16 + q15)*64 + g*8;
      h8 k0 = *(const h8*)(kr);
      h8 k1 = *(const h8*)(kr + 32);
      fx4 sc = zero4;
      sc = MFMA16(k0, qf[0], sc);
      sc = MFMA16(k1, qf[1], sc);
      S[kf] = sc;   // C[kv, q]: q = lane&15, kv = kf*16 + g*4 + r
    }
    float tm = S[0][0];
    #pragma unroll
    for (int kf=0;kf<4;++kf)
      #pragma unroll
      for (int r=0;r<4;++r) tm = fmaxf(tm, S[kf][r]);
    tm = fmaxf(tm, __shfl_xor(tm, 16));
    tm = fmaxf(tm, __shfl_xor(tm, 32));
    float mnew = fmaxf(m_run, tm);
    float fac = exp2f((m_run - mnew)*L2E);
    float p[4][4]; float ts = 0.f;
    #pragma unroll
    for (int kf=0;kf<4;++kf)
      #pragma unroll
      for (int r=0;r<4;++r){
        float e = exp2f((S[kf][r]-mnew)*L2E);
        p[kf][r] = e; ts += e;
      }
    ts += __shfl_xor(ts, 16);
    ts += __shfl_xor(ts, 32);
    l_run = l_run*fac + ts;
    m_run = mnew;
    // rescale O (O-frag rows are q = g*4+r -> fetch per-row factors)
    float fr[4];
    #pragma unroll
    for (int r=0;r<4;++r) fr[r] = __shfl(fac, g*4 + r);
    #pragma unroll
    for (int df=0;df<4;++df)
      #pragma unroll
      for (int r=0;r<4;++r) oacc[df][r] *= fr[r];
    // redistribute P from C-layout to A-frag layout (kv = 8g+jj per lane)
    h8 pfr[2];
    #pragma unroll
    for (int kw=0; kw<2; ++kw){
      uint32_t pa0 = pkh(p[2*kw][0],   p[2*kw][1]);
      uint32_t pa1 = pkh(p[2*kw][2],   p[2*kw][3]);
      uint32_t pb0 = pkh(p[2*kw+1][0], p[2*kw+1][1]);
      uint32_t pb1 = pkh(p[2*kw+1][2], p[2*kw+1][3]);
      int src0 = q15 + ((g&1)<<5);
      int src1 = src0 + 16;
      uint32_t t00 = __shfl(pa0, src0), t01 = __shfl(pb0, src0);
      uint32_t t10 = __shfl(pa1, src0), t11 = __shfl(pb1, src0);
      uint32_t t20 = __shfl(pa0, src1), t21 = __shfl(pb0, src1);
      uint32_t t30 = __shfl(pa1, src1), t31 = __shfl(pb1, src1);
      bool hi = (g >= 2);
      union { uint32_t u[4]; h8 v; } cvv;
      cvv.u[0] = hi ? t01 : t00;
      cvv.u[1] = hi ? t11 : t10;
      cvv.u[2] = hi ? t21 : t20;
      cvv.u[3] = hi ? t31 : t30;
      pfr[kw] = cvv.v;
    }
    // PV: O[q, d] += P[q, kv] * V[kv, d]   (V read from transposed Vt rows: contiguous)
    #pragma unroll
    for (int kw=0; kw<2; ++kw)
      #pragma unroll
      for (int df=0; df<4; ++df){
        const u16* vr = Vp + (((size_t)(df*16 + q15))<<11) + kv0 + kw*32 + g*8;
        h8 vf = *(const h8*)(vr);
        oacc[df] = MFMA16(pfr[kw], vf, oacc[df]);
      }
  }
  float linv = 1.f / l_run;
  float lr[4];
  #pragma unroll
  for (int r=0;r<4;++r) lr[r] = __shfl(linv, g*4 + r);
  #pragma unroll
  for (int df=0; df<4; ++df)
    #pragma unroll
    for (int r=0; r<4; ++r){
      int q = q0 + g*4 + r;
      Ob[(((size_t)(b*2048 + q))<<10) + h*64 + df*16 + q15] = f2hbits(oacc[df][r]*lr[r]);
    }
}

extern "C" void kernel_launch(void* const* d_in, const int* in_sizes, int n_in,
                              void* d_out, int out_size, void* d_ws, size_t ws_size,
                              hipStream_t stream) {
  const float* x    = (const float*)d_in[0];
  const float* Wq   = (const float*)d_in[1];
  const float* bq   = (const float*)d_in[2];
  const float* Wk   = (const float*)d_in[3];
  const float* bk   = (const float*)d_in[4];
  const float* Wv   = (const float*)d_in[5];
  const float* bv   = (const float*)d_in[6];
  const float* WO_w = (const float*)d_in[7];
  const float* WO_b = (const float*)d_in[8];

  char* ws = (char*)d_ws;
  u16* x16  = (u16*)(ws);                    // 16,777,216 B
  u16* Wt   = (u16*)(ws + 16777216);         //  6,291,456 B
  u16* WO16 = (u16*)(ws + 23068672);         //  2,097,152 B
  u16* Qb   = (u16*)(ws + 25165824);         // 16,777,216 B
  u16* Kb   = (u16*)(ws + 41943040);         // 16,777,216 B
  u16* Vtb  = (u16*)(ws + 58720256);         // 16,777,216 B
  u16* Ob   = (u16*)(ws + 75497472);         // 16,777,216 B  (total ~88 MB)

  f2h_kernel<<<8192, 256, 0, stream>>>(x, x16, 2097152);
  f2h_kernel<<<1024, 256, 0, stream>>>(WO_w, WO16, 262144);
  wtr_kernel<<<dim3(16,16,3), 256, 0, stream>>>(Wq, Wk, Wv, Wt);
  gemm_nt<0><<<dim3(64,8,3), 256, 0, stream>>>(x16, Wt, bq, bk, bv, Qb, Kb, Vtb, nullptr);
  attn_kernel<<<2048, 256, 0, stream>>>(Qb, Kb, Vtb, Ob);
  gemm_nt<1><<<dim3(8,16,4), 256, 0, stream>>>(WO16, Ob, WO_b, nullptr, nullptr,
                                               nullptr, nullptr, nullptr, (float*)d_out);
}

// Round 2
// 341.555 us; speedup vs baseline: 1.6154x; 1.6154x over previous
//
#include <hip/hip_runtime.h>
#include <hip/hip_fp16.h>

typedef unsigned short u16;
typedef __attribute__((ext_vector_type(8))) _Float16 h8;
typedef __attribute__((ext_vector_type(8))) short s16x8;
typedef __attribute__((ext_vector_type(4))) float fx4;
typedef __attribute__((ext_vector_type(16))) float f32x16;

#define MFMA16(a,b,c) __builtin_amdgcn_mfma_f32_16x16x32_f16((a),(b),(c),0,0,0)
#define MFMA32(a,b,c) __builtin_amdgcn_mfma_f32_32x32x16_f16((a),(b),(c),0,0,0)

static __device__ __forceinline__ u16 f2hbits(float x){
  __half h = __float2half_rn(x);
  union { __half h; u16 u; } c; c.h = h; return c.u;
}
static __device__ __forceinline__ uint32_t pkh(float a, float b){
  __half2 h = __floats2half2_rn(a, b);
  union { __half2 h; uint32_t u; } c; c.h = h; return c.u;
}

// ---------------- prep: fp32 -> fp16 cast ----------------
__global__ void f2h_kernel(const float* __restrict__ in, u16* __restrict__ out, int n4){
  int i = blockIdx.x*256 + threadIdx.x;
  if (i < n4){
    float4 v = ((const float4*)in)[i];
    ushort4 o;
    o.x = f2hbits(v.x); o.y = f2hbits(v.y); o.z = f2hbits(v.z); o.w = f2hbits(v.w);
    ((ushort4*)out)[i] = o;
  }
}

// ---------------- prep: W[h][n][d] -> Wt[h*64+d][n] fp16 ----------------
__global__ void wtr_kernel(const float* __restrict__ Wq, const float* __restrict__ Wk,
                           const float* __restrict__ Wv, u16* __restrict__ Wt){
  __shared__ float tl[64][65];
  int z = blockIdx.z, h = blockIdx.y, n0 = blockIdx.x*64;
  const float* W = (z==0)?Wq:((z==1)?Wk:Wv);
  W += (size_t)h*65536;  // h * 1024 * 64
  int t = threadIdx.x;
  #pragma unroll
  for (int i=0;i<16;++i){
    int idx = t + i*256; int r = idx>>6, c = idx&63;
    tl[r][c] = W[(size_t)(n0+r)*64 + c];
  }
  __syncthreads();
  u16* O = Wt + (size_t)z*1048576 + (size_t)h*64*1024 + n0;
  #pragma unroll
  for (int i=0;i<16;++i){
    int idx = t + i*256; int r2 = idx>>6, c2 = idx&63;
    O[(size_t)r2*1024 + c2] = f2hbits(tl[c2][r2]);
  }
}

// ---------------- 128x128x(K=1024) NT GEMM, fp16 MFMA, reg-staged dbuf ----------------
template<int EPI>
__launch_bounds__(256, 2)
__global__ void gemm_nt(const u16* __restrict__ A, const u16* __restrict__ Bbase,
                        const float* __restrict__ bias0, const float* __restrict__ bias1,
                        const float* __restrict__ bias2,
                        u16* __restrict__ out0, u16* __restrict__ out1, u16* __restrict__ out2,
                        float* __restrict__ fout){
  __shared__ __align__(16) u16 lds[16384];
  const int K = 1024;
  int mt = blockIdx.x, ntile = blockIdx.y, z = blockIdx.z;
  int m0 = mt*128, n0 = ntile*128;
  const u16* Ap = A;
  const u16* Bp = (EPI==0) ? (Bbase + (size_t)z*1048576) : (Bbase + (size_t)z*2097152);
  int t = threadIdx.x;
  int lane = t & 63, wv = t>>6, g = lane>>4, q15 = lane&15;
  int wr = wv>>1, wc = wv&1;

  fx4 zero4 = {0.f,0.f,0.f,0.f};
  fx4 acc[4][4];
  #pragma unroll
  for (int i=0;i<4;++i)
    #pragma unroll
    for (int j=0;j<4;++j) acc[i][j] = zero4;

  int rowA = t>>2, col8 = (t&3)*8;
  const u16* gA0 = Ap + (size_t)(m0+rowA)*K + col8;
  const u16* gA1 = Ap + (size_t)(m0+rowA+64)*K + col8;
  const u16* gB0 = Bp + (size_t)(n0+rowA)*K + col8;
  const u16* gB1 = Bp + (size_t)(n0+rowA+64)*K + col8;

  s16x8 sa0 = *(const s16x8*)(gA0);
  s16x8 sa1 = *(const s16x8*)(gA1);
  s16x8 sb0 = *(const s16x8*)(gB0);
  s16x8 sb1 = *(const s16x8*)(gB1);
  int cur = 0;
  *(s16x8*)(lds + t*8)        = sa0;
  *(s16x8*)(lds + 2048 + t*8) = sa1;
  *(s16x8*)(lds + 4096 + t*8) = sb0;
  *(s16x8*)(lds + 6144 + t*8) = sb1;

  for (int kt=0; kt<32; ++kt){
    if (kt+1 < 32){
      int k0 = (kt+1)*32;
      sa0 = *(const s16x8*)(gA0 + k0);
      sa1 = *(const s16x8*)(gA1 + k0);
      sb0 = *(const s16x8*)(gB0 + k0);
      sb1 = *(const s16x8*)(gB1 + k0);
    }
    __syncthreads();
    const u16* bufA = lds + cur*8192;
    const u16* bufB = bufA + 4096;
    h8 af[4], bf[4];
    #pragma unroll
    for (int f=0; f<4; ++f)
      af[f] = *(const h8*)(bufA + (wr*64 + f*16 + q15)*32 + g*8);
    #pragma unroll
    for (int f=0; f<4; ++f)
      bf[f] = *(const h8*)(bufB + (wc*64 + f*16 + q15)*32 + g*8);
    #pragma unroll
    for (int i=0;i<4;++i)
      #pragma unroll
      for (int j=0;j<4;++j)
        acc[i][j] = MFMA16(af[i], bf[j], acc[i][j]);
    if (kt+1 < 32){
      u16* nb = lds + (cur^1)*8192;
      *(s16x8*)(nb + t*8)        = sa0;
      *(s16x8*)(nb + 2048 + t*8) = sa1;
      *(s16x8*)(nb + 4096 + t*8) = sb0;
      *(s16x8*)(nb + 6144 + t*8) = sb1;
      cur ^= 1;
    }
  }

  if constexpr (EPI==0){
    const float* bias = (z==0)?bias0:((z==1)?bias1:bias2);
    float bcol[4];
    #pragma unroll
    for (int fj=0;fj<4;++fj) bcol[fj] = bias[n0 + wc*64 + fj*16 + q15];
    int bb = m0 >> 11;
    int s_base = (m0 & 2047) + wr*64;
    if (z < 2){
      u16* o = (z==0)? out0 : out1;
      float sc = (z==0)? 0.125f : 1.0f;
      #pragma unroll
      for (int fi=0;fi<4;++fi)
        #pragma unroll
        for (int fj=0;fj<4;++fj){
          int n = n0 + wc*64 + fj*16 + q15;
          int hh = n>>6, d = n&63;
          #pragma unroll
          for (int r=0;r<4;++r){
            int s = s_base + fi*16 + g*4 + r;
            float v = (acc[fi][fj][r] + bcol[fj]) * sc;
            o[(((size_t)(bb*16+hh)*2048 + s)<<6) + d] = f2hbits(v);
          }
        }
    } else {
      #pragma unroll
      for (int fi=0;fi<4;++fi)
        #pragma unroll
        for (int fj=0;fj<4;++fj){
          int n = n0 + wc*64 + fj*16 + q15;
          int hh = n>>6, d = n&63;
          int s = s_base + fi*16 + g*4;
          ushort4 pk;
          pk.x = f2hbits(acc[fi][fj][0] + bcol[fj]);
          pk.y = f2hbits(acc[fi][fj][1] + bcol[fj]);
          pk.z = f2hbits(acc[fi][fj][2] + bcol[fj]);
          pk.w = f2hbits(acc[fi][fj][3] + bcol[fj]);
          *(ushort4*)(out2 + (((size_t)((bb*16+hh)*64 + d))<<11) + s) = pk;
        }
    }
  } else {
    int bb = z;
    float brow[4][4];
    #pragma unroll
    for (int fi=0;fi<4;++fi)
      #pragma unroll
      for (int r=0;r<4;++r) brow[fi][r] = bias0[m0 + wr*64 + fi*16 + g*4 + r];
    #pragma unroll
    for (int fi=0;fi<4;++fi)
      #pragma unroll
      for (int fj=0;fj<4;++fj){
        int scol = n0 + wc*64 + fj*16 + q15;
        #pragma unroll
        for (int r=0;r<4;++r){
          int orow = m0 + wr*64 + fi*16 + g*4 + r;
          fout[((size_t)bb<<21) + ((size_t)orow<<11) + scol] = acc[fi][fj][r] + brow[fi][r];
        }
      }
  }
}

// ---------------- flash attention, 32x32 swapped structure ----------------
// Per wave: 32 q-rows, full KV sweep in 32-row tiles. No LDS, no barriers.
// S^T = mfma(K, Q^T): C col = q = lane&31 -> softmax per-lane + one shfl_xor(32).
// O^T = mfma(V^T, P^T): consumes Vt[b][h][d][s] rows directly.
__launch_bounds__(256)
__global__ void attn_kernel(const u16* __restrict__ Qb, const u16* __restrict__ Kb,
                            const u16* __restrict__ Vt, u16* __restrict__ Ob){
  int bid = blockIdx.x;
  int qb = bid & 15, h = (bid>>4)&15, b = bid>>8;
  int t = threadIdx.x;
  int lane = t&63, wv = t>>6;
  int l31 = lane&31, hi = lane>>5;
  size_t bh = (size_t)(b*16 + h);
  const u16* Qp = Qb + (bh<<17);   // [2048][64]
  const u16* Kp = Kb + (bh<<17);   // [2048][64]
  const u16* Vp = Vt + (bh<<17);   // [64][2048]
  int q0 = qb*128 + wv*32;
  const float L2E = 1.44269504f;

  // Q fragments (B-operand): col=q=lane&31, k = s*16 + hi*8 + j
  h8 qf[4];
  #pragma unroll
  for (int s=0;s<4;++s)
    qf[s] = *(const h8*)(Qp + (size_t)(q0+l31)*64 + s*16 + hi*8);

  f32x16 o0, o1;
  #pragma unroll
  for (int i=0;i<16;++i){ o0[i]=0.f; o1[i]=0.f; }
  float m_run = -1e30f, l_run = 0.f;

  for (int kt=0; kt<64; ++kt){
    int kv0 = kt*32;
    // K fragments (A-operand): row=kv=lane&31, k = s*16 + hi*8 + j
    h8 kf[4];
    #pragma unroll
    for (int s=0;s<4;++s)
      kf[s] = *(const h8*)(Kp + (size_t)(kv0+l31)*64 + s*16 + hi*8);
    f32x16 S;
    #pragma unroll
    for (int i=0;i<16;++i) S[i]=0.f;
    #pragma unroll
    for (int s=0;s<4;++s) S = MFMA32(kf[s], qf[s], S);
    // S[i]: kv = (i&3) + 8*(i>>2) + 4*hi (local), q = lane&31

    // tile max (tree) + cross-half combine
    float t8[8];
    #pragma unroll
    for (int i=0;i<8;++i) t8[i] = fmaxf(S[i], S[i+8]);
    float t4a = fmaxf(t8[0],t8[4]), t4b = fmaxf(t8[1],t8[5]);
    float t4c = fmaxf(t8[2],t8[6]), t4d = fmaxf(t8[3],t8[7]);
    float tm = fmaxf(fmaxf(t4a,t4b), fmaxf(t4c,t4d));
    tm = fmaxf(tm, __shfl_xor(tm, 32));

    // defer-max (T13): only rescale when tile max grew past threshold
    if (!__all(tm - m_run <= 8.f)){
      float mnew = fmaxf(m_run, tm);
      float fac = exp2f((m_run - mnew)*L2E);
      #pragma unroll
      for (int i=0;i<16;++i){ o0[i]*=fac; o1[i]*=fac; }
      l_run *= fac;
      m_run = mnew;
    }
    float mL2 = m_run * L2E;
    float p[16]; float s8[8];
    #pragma unroll
    for (int i=0;i<16;++i) p[i] = exp2f(__builtin_fmaf(S[i], L2E, -mL2));
    #pragma unroll
    for (int i=0;i<8;++i) s8[i] = p[i] + p[i+8];
    float ts = ((s8[0]+s8[4]) + (s8[1]+s8[5])) + ((s8[2]+s8[6]) + (s8[3]+s8[7]));
    ts += __shfl_xor(ts, 32);
    l_run += ts;

    // P -> B-frag (P^T) redistribution: per 16-kv step, exchange one packed
    // pair across the lane^32 split. p[i] holds kv = (i&3)+8*(i>>2)+4*hi.
    #pragma unroll
    for (int tt=0; tt<2; ++tt){
      uint32_t A0 = pkh(p[8*tt+0], p[8*tt+1]);
      uint32_t A1 = pkh(p[8*tt+2], p[8*tt+3]);
      uint32_t B0 = pkh(p[8*tt+4], p[8*tt+5]);
      uint32_t B1 = pkh(p[8*tt+6], p[8*tt+7]);
      uint32_t s0 = hi ? A0 : B0, s1 = hi ? A1 : B1;
      uint32_t r0 = __shfl_xor(s0, 32), r1 = __shfl_xor(s1, 32);
      union { uint32_t u[4]; h8 v; } pf;
      pf.u[0] = hi ? r0 : A0;
      pf.u[1] = hi ? r1 : A1;
      pf.u[2] = hi ? B0 : r0;
      pf.u[3] = hi ? B1 : r1;
      // V A-frags: row = d_local = lane&31, k = kv_local = hi*8 + j
      h8 v0 = *(const h8*)(Vp + ((size_t)l31<<11)        + kv0 + tt*16 + hi*8);
      h8 v1 = *(const h8*)(Vp + ((size_t)(32+l31)<<11)   + kv0 + tt*16 + hi*8);
      o0 = MFMA32(v0, pf.v, o0);
      o1 = MFMA32(v1, pf.v, o1);
    }
  }

  float linv = 1.f / l_run;
  // o{0,1}[i]: d = 32*dt + (i&3) + 8*(i>>2) + 4*hi ; q = lane&31
  u16* obase = Ob + ((size_t)(b*2048 + q0 + l31))*1024 + h*64 + hi*4;
  #pragma unroll
  for (int u=0; u<4; ++u){
    ushort4 w0, w1;
    w0.x = f2hbits(o0[4*u+0]*linv); w0.y = f2hbits(o0[4*u+1]*linv);
    w0.z = f2hbits(o0[4*u+2]*linv); w0.w = f2hbits(o0[4*u+3]*linv);
    w1.x = f2hbits(o1[4*u+0]*linv); w1.y = f2hbits(o1[4*u+1]*linv);
    w1.z = f2hbits(o1[4*u+2]*linv); w1.w = f2hbits(o1[4*u+3]*linv);
    *(ushort4*)(obase + u*8)      = w0;
    *(ushort4*)(obase + 32 + u*8) = w1;
  }
}

extern "C" void kernel_launch(void* const* d_in, const int* in_sizes, int n_in,
                              void* d_out, int out_size, void* d_ws, size_t ws_size,
                              hipStream_t stream) {
  const float* x    = (const float*)d_in[0];
  const float* Wq   = (const float*)d_in[1];
  const float* bq   = (const float*)d_in[2];
  const float* Wk   = (const float*)d_in[3];
  const float* bk   = (const float*)d_in[4];
  const float* Wv   = (const float*)d_in[5];
  const float* bv   = (const float*)d_in[6];
  const float* WO_w = (const float*)d_in[7];
  const float* WO_b = (const float*)d_in[8];

  char* ws = (char*)d_ws;
  u16* x16  = (u16*)(ws);
  u16* Wt   = (u16*)(ws + 16777216);
  u16* WO16 = (u16*)(ws + 23068672);
  u16* Qb   = (u16*)(ws + 25165824);
  u16* Kb   = (u16*)(ws + 41943040);
  u16* Vtb  = (u16*)(ws + 58720256);
  u16* Ob   = (u16*)(ws + 75497472);

  f2h_kernel<<<8192, 256, 0, stream>>>(x, x16, 2097152);
  f2h_kernel<<<1024, 256, 0, stream>>>(WO_w, WO16, 262144);
  wtr_kernel<<<dim3(16,16,3), 256, 0, stream>>>(Wq, Wk, Wv, Wt);
  gemm_nt<0><<<dim3(64,8,3), 256, 0, stream>>>(x16, Wt, bq, bk, bv, Qb, Kb, Vtb, nullptr);
  attn_kernel<<<1024, 256, 0, stream>>>(Qb, Kb, Vtb, Ob);
  gemm_nt<1><<<dim3(8,16,4), 256, 0, stream>>>(WO16, Ob, WO_b, nullptr, nullptr,
                                               nullptr, nullptr, nullptr, (float*)d_out);
}